// Round 6
// baseline (120.664 us; speedup 1.0000x reference)
//
#include <hip/hip_runtime.h>

// B=1, H=W=128, C=1280; HW=16384 pixels, 19 relation channels, 1024 keys.
//
// Algebra: x_m = (v2@v1)·x   (M1: 19x1280, stored transposed m1t[c][o])
//          cab = softmax(x_m·imt^T)·im2, im2 = imt@inter  (1024x19)
//          out = relu((w2@w1)·cab) + x  (M2 stored transposed m2t[d][o])
//
// ws layout (floats):
//   m1t : [1280][20] (pad)       off 0       len 25600   (M1^T: m1t[c][o])
//   m2t : [19][1280]             off 25600   len 24320   (m2t[d][o])
//   imt : [1024][20] (pad)       off 49920   len 20480   (intra[i]^T)
//   im2 : [1024][20] (pad)       off 70400   len 20480   (imt @ inter[i])
//   xm  : flat 19*16384          off 90880   len 311296  (o-major; reinterpreted n-major)
//   cab : flat 16384*19          off 402176  len 311296  (n-major; reinterpreted d-major)

#define OFF_M2T 25600
#define OFF_IMT 49920
#define OFF_IM2 70400
#define OFF_XM  90880
#define OFF_CAB 402176

typedef float vf4 __attribute__((ext_vector_type(4)));

// prep: weight folds + transposes + cls-row copy (independent of everything else)
__global__ __launch_bounds__(256) void prep_kernel(
    const float* __restrict__ v1, const float* __restrict__ v2,
    const float* __restrict__ w1, const float* __restrict__ w2,
    const float* __restrict__ intra, const float* __restrict__ inter,
    const int* __restrict__ ip, const float* __restrict__ x,
    float* __restrict__ out, float* __restrict__ ws)
{
  float* m1t = ws;
  float* m2t = ws + OFF_M2T;
  float* imt = ws + OFF_IMT;
  float* im2 = ws + OFF_IM2;
  const int blk = blockIdx.x, tid = threadIdx.x;
  if (blk < 380) {
    // M1[o][j] = sum_c v2[o][c]*v1[c][j] -> stored m1t[j][o], 4-way c-split
    int g = blk * 256 + tid;
    int oidx = g >> 2, part = g & 3;
    int o = oidx / 1280, j = oidx - o * 1280;
    const float* v2r = v2 + o * 512 + part * 128;
    const float* v1c = v1 + part * 128 * 1280 + j;
    float acc = 0.f;
#pragma unroll 8
    for (int c = 0; c < 128; ++c) acc = fmaf(v2r[c], v1c[c * 1280], acc);
    acc += __shfl_xor(acc, 1);
    acc += __shfl_xor(acc, 2);
    if (part == 0) {
      m1t[j * 20 + o] = acc;
      if (o == 0) m1t[j * 20 + 19] = 0.f;
    }
  } else if (blk < 760) {
    // M2t[d][o] = sum_c w2[o][c]*w1[c][d]
    int g = (blk - 380) * 256 + tid;
    int oidx = g >> 2, part = g & 3;
    int o = oidx / 19, d = oidx - o * 19;
    const float* w2r = w2 + o * 512 + part * 128;
    const float* w1c = w1 + part * 128 * 19 + d;
    float acc = 0.f;
#pragma unroll 8
    for (int c = 0; c < 128; ++c) acc = fmaf(w2r[c], w1c[c * 19], acc);
    acc += __shfl_xor(acc, 1);
    acc += __shfl_xor(acc, 2);
    if (part == 0) m2t[d * 1280 + o] = acc;
  } else if (blk < 836) {
    // imt[k][c] = intra[i][c][k]
    int t = (blk - 760) * 256 + tid;
    int c = t >> 10, k = t & 1023;
    int iv = *ip;
    imt[k * 20 + c] = intra[(size_t)iv * 19456 + c * 1024 + k];
    if (c == 0) imt[k * 20 + 19] = 0.f;
  } else if (blk < 912) {
    // im2[k][d] = sum_c intra[i][c][k]*inter[i][c][d]
    int t = (blk - 836) * 256 + tid;
    int d = t >> 10, k = t & 1023;
    int iv = *ip;
    const float* ib = intra + (size_t)iv * 19456 + k;
    const float* ir = inter + (size_t)iv * 361 + d;
    float acc = 0.f;
#pragma unroll
    for (int c = 0; c < 19; ++c) acc = fmaf(ib[c * 1024], ir[c * 19], acc);
    im2[k * 20 + d] = acc;
    if (d == 0) im2[k * 20 + 19] = 0.f;
  } else {
    // cls row copy: out[0][w][c] = x[0][w][c], 40960 float4; 40 blocks x 4 each
    const float4* xf = reinterpret_cast<const float4*>(x);
    float4* of = reinterpret_cast<float4*>(out);
    const int base = (blk - 912) * 1024 + tid;
#pragma unroll
    for (int q = 0; q < 4; ++q) of[base + q * 256] = xf[base + q * 256];
  }
}

#define XM_FMA19(XC, W)                                                  \
  a00 = fmaf((XC), (W)[0],  a00); a01 = fmaf((XC), (W)[1],  a01);        \
  a02 = fmaf((XC), (W)[2],  a02); a03 = fmaf((XC), (W)[3],  a03);        \
  a04 = fmaf((XC), (W)[4],  a04); a05 = fmaf((XC), (W)[5],  a05);        \
  a06 = fmaf((XC), (W)[6],  a06); a07 = fmaf((XC), (W)[7],  a07);        \
  a08 = fmaf((XC), (W)[8],  a08); a09 = fmaf((XC), (W)[9],  a09);        \
  a10 = fmaf((XC), (W)[10], a10); a11 = fmaf((XC), (W)[11], a11);        \
  a12 = fmaf((XC), (W)[12], a12); a13 = fmaf((XC), (W)[13], a13);        \
  a14 = fmaf((XC), (W)[14], a14); a15 = fmaf((XC), (W)[15], a15);        \
  a16 = fmaf((XC), (W)[16], a16); a17 = fmaf((XC), (W)[17], a17);        \
  a18 = fmaf((XC), (W)[18], a18);

// K2: xm[o][hw] = sum_c M1[o][c]*x[hw+128][c].
// Block = 64 px. 10 chunks of 128 c. Reg-staged double-buffered LDS transpose;
// ONE barrier per chunk; named scalar accumulators (registers, no scratch).
__global__ __launch_bounds__(1024) void xm_kernel(
    const float* __restrict__ x, const float* __restrict__ m1t,
    float* __restrict__ xm)
{
  __shared__ float sbuf[19456];                 // 76 KB: 2x8192 stage, then reduce
  const int blk = blockIdx.x, tid = threadIdx.x;
  const int p  = tid & 63;
  const int kp = tid >> 6;
  const int kpu = __builtin_amdgcn_readfirstlane(kp);
  const int n0 = blk * 64;
  const float* xg = x + (size_t)(n0 + 128) * 1280;

  const int px0 = tid >> 5, g0 = tid & 31;
  const int px1 = px0 + 32;
  const size_t ga0 = (size_t)px0 * 1280 + g0 * 4;
  const size_t ga1 = (size_t)px1 * 1280 + g0 * 4;
  const int st0 = px0 * 128 + (((g0 + px0) & 31) << 2);
  const int st1 = px1 * 128 + (((g0 + px1) & 31) << 2);
  const int rd0 = p * 128 + ((((kpu * 2 + 0) + p) & 31) << 2);
  const int rd1 = p * 128 + ((((kpu * 2 + 1) + p) & 31) << 2);

  float a00 = 0.f, a01 = 0.f, a02 = 0.f, a03 = 0.f, a04 = 0.f;
  float a05 = 0.f, a06 = 0.f, a07 = 0.f, a08 = 0.f, a09 = 0.f;
  float a10 = 0.f, a11 = 0.f, a12 = 0.f, a13 = 0.f, a14 = 0.f;
  float a15 = 0.f, a16 = 0.f, a17 = 0.f, a18 = 0.f;

  {
    const float4 r0 = *reinterpret_cast<const float4*>(xg + ga0);
    const float4 r1 = *reinterpret_cast<const float4*>(xg + ga1);
    *reinterpret_cast<float4*>(sbuf + st0) = r0;
    *reinterpret_cast<float4*>(sbuf + st1) = r1;
  }
  __syncthreads();

  for (int cc = 0; cc < 10; ++cc) {
    float4 n0v, n1v;
    if (cc < 9) {                    // issue next-chunk loads early
      n0v = *reinterpret_cast<const float4*>(xg + ga0 + (cc + 1) * 128);
      n1v = *reinterpret_cast<const float4*>(xg + ga1 + (cc + 1) * 128);
    }
    const float* buf = sbuf + (cc & 1) * 8192;
    const float4 xv0 = *reinterpret_cast<const float4*>(buf + rd0);
    const float4 xv1 = *reinterpret_cast<const float4*>(buf + rd1);
    const float* wrow = m1t + (cc * 128 + kpu * 8) * 20;   // uniform -> s_load
    XM_FMA19(xv0.x, wrow);
    XM_FMA19(xv0.y, wrow + 20);
    XM_FMA19(xv0.z, wrow + 40);
    XM_FMA19(xv0.w, wrow + 60);
    XM_FMA19(xv1.x, wrow + 80);
    XM_FMA19(xv1.y, wrow + 100);
    XM_FMA19(xv1.z, wrow + 120);
    XM_FMA19(xv1.w, wrow + 140);
    if (cc < 9) {
      float* nbuf = sbuf + ((cc + 1) & 1) * 8192;
      *reinterpret_cast<float4*>(nbuf + st0) = n0v;
      *reinterpret_cast<float4*>(nbuf + st1) = n1v;
    }
    __syncthreads();
  }

  {
    float* rb = sbuf + kp * 1216 + p * 19;
    rb[0] = a00;  rb[1] = a01;  rb[2] = a02;  rb[3] = a03;  rb[4] = a04;
    rb[5] = a05;  rb[6] = a06;  rb[7] = a07;  rb[8] = a08;  rb[9] = a09;
    rb[10] = a10; rb[11] = a11; rb[12] = a12; rb[13] = a13; rb[14] = a14;
    rb[15] = a15; rb[16] = a16; rb[17] = a17; rb[18] = a18;
  }
  __syncthreads();
  for (int idx = tid; idx < 1216; idx += 1024) {
    const int o = idx >> 6, pp = idx & 63;
    float s = 0.f;
#pragma unroll
    for (int q = 0; q < 16; ++q) s += sbuf[q * 1216 + pp * 19 + o];
    xm[o * 16384 + n0 + pp] = s;
  }
}

#define SOFT_ACC19(PV, U)                                                \
  o00 = fmaf((PV), (U)[0],  o00); o01 = fmaf((PV), (U)[1],  o01);        \
  o02 = fmaf((PV), (U)[2],  o02); o03 = fmaf((PV), (U)[3],  o03);        \
  o04 = fmaf((PV), (U)[4],  o04); o05 = fmaf((PV), (U)[5],  o05);        \
  o06 = fmaf((PV), (U)[6],  o06); o07 = fmaf((PV), (U)[7],  o07);        \
  o08 = fmaf((PV), (U)[8],  o08); o09 = fmaf((PV), (U)[9],  o09);        \
  o10 = fmaf((PV), (U)[10], o10); o11 = fmaf((PV), (U)[11], o11);        \
  o12 = fmaf((PV), (U)[12], o12); o13 = fmaf((PV), (U)[13], o13);        \
  o14 = fmaf((PV), (U)[14], o14); o15 = fmaf((PV), (U)[15], o15);        \
  o16 = fmaf((PV), (U)[16], o16); o17 = fmaf((PV), (U)[17], o17);        \
  o18 = fmaf((PV), (U)[18], o18);

// K3: per row n: s_k = xv.imt[k]; p=exp(s); Z+=p; outd += p*im2[k];
// cab[n][d] = outd/Z. 512 thr / 8 waves (45 KB LDS -> 2 blocks/CU), k-slice=128.
__global__ __launch_bounds__(512) void soft_kernel(
    const float* __restrict__ xm, const float* __restrict__ imt,
    const float* __restrict__ im2, float* __restrict__ cab)
{
  __shared__ float red[8][64][20];
  __shared__ float xstage[1216];
  const int blk = blockIdx.x, tid = threadIdx.x;
  const int r = tid & 63, kp = tid >> 6;
  const int kpu = __builtin_amdgcn_readfirstlane(kp);
  const int n0 = blk * 64;

  for (int idx = tid; idx < 1216; idx += 512)
    xstage[idx] = xm[(size_t)n0 * 19 + idx];
  __syncthreads();

  const float* xr = xstage + r * 19;
  const float x00 = xr[0],  x01 = xr[1],  x02 = xr[2],  x03 = xr[3];
  const float x04 = xr[4],  x05 = xr[5],  x06 = xr[6],  x07 = xr[7];
  const float x08 = xr[8],  x09 = xr[9],  x10 = xr[10], x11 = xr[11];
  const float x12 = xr[12], x13 = xr[13], x14 = xr[14], x15 = xr[15];
  const float x16 = xr[16], x17 = xr[17], x18 = xr[18];

  float o00 = 0.f, o01 = 0.f, o02 = 0.f, o03 = 0.f, o04 = 0.f;
  float o05 = 0.f, o06 = 0.f, o07 = 0.f, o08 = 0.f, o09 = 0.f;
  float o10 = 0.f, o11 = 0.f, o12 = 0.f, o13 = 0.f, o14 = 0.f;
  float o15 = 0.f, o16 = 0.f, o17 = 0.f, o18 = 0.f;
  float Z = 0.f;
  const int kbase = kpu * 128;
  for (int k = kbase; k < kbase + 128; ++k) {
    const float* w = imt + k * 20;       // wave-uniform -> scalar loads
    const float* u = im2 + k * 20;
    float s0 = x00 * w[0];
    s0 = fmaf(x04, w[4], s0); s0 = fmaf(x08, w[8],  s0);
    s0 = fmaf(x12, w[12], s0); s0 = fmaf(x16, w[16], s0);
    float s1 = x01 * w[1];
    s1 = fmaf(x05, w[5], s1); s1 = fmaf(x09, w[9],  s1);
    s1 = fmaf(x13, w[13], s1); s1 = fmaf(x17, w[17], s1);
    float s2 = x02 * w[2];
    s2 = fmaf(x06, w[6], s2); s2 = fmaf(x10, w[10], s2);
    s2 = fmaf(x14, w[14], s2); s2 = fmaf(x18, w[18], s2);
    float s3 = x03 * w[3];
    s3 = fmaf(x07, w[7], s3); s3 = fmaf(x11, w[11], s3);
    s3 = fmaf(x15, w[15], s3);
    const float s = (s0 + s1) + (s2 + s3);
    const float pv = __expf(s);
    Z += pv;
    SOFT_ACC19(pv, u);
  }
  {
    float* rb = &red[kp][r][0];
    rb[0] = o00;  rb[1] = o01;  rb[2] = o02;  rb[3] = o03;  rb[4] = o04;
    rb[5] = o05;  rb[6] = o06;  rb[7] = o07;  rb[8] = o08;  rb[9] = o09;
    rb[10] = o10; rb[11] = o11; rb[12] = o12; rb[13] = o13; rb[14] = o14;
    rb[15] = o15; rb[16] = o16; rb[17] = o17; rb[18] = o18; rb[19] = Z;
  }
  __syncthreads();
  for (int idx = tid; idx < 64 * 19; idx += 512) {
    int rr = idx / 19, d = idx % 19;
    float s = 0.f, Zs = 0.f;
#pragma unroll
    for (int q = 0; q < 8; ++q) { s += red[q][rr][d]; Zs += red[q][rr][19]; }
    cab[(size_t)blk * 64 * 19 + idx] = s / Zs;   // (blk*64+rr)*19+d
  }
}

// K4: out[hw+128 row][c] = relu(sum_d m2t[d][c]*cabD[d][hw]) + x[..][c]
// cabD[d][hw] = cab_flat[d*16384+hw] (reshape reinterpretation).
// 2048 blocks x 8 px; thread owns channel-quad; cab via uniform s_loads;
// x preloaded 4-deep; PLAIN float4 stores (nt-store A/B probe: nt reverted).
__global__ __launch_bounds__(320, 4) void out_kernel(
    const float* __restrict__ x, const float* __restrict__ m2t,
    const float* __restrict__ cab, float* __restrict__ out)
{
  const int blk = blockIdx.x, tid = threadIdx.x;
  const int c4 = tid * 4;
  float4 mq[19];
#pragma unroll
  for (int d = 0; d < 19; ++d)
    mq[d] = *reinterpret_cast<const float4*>(m2t + d * 1280 + c4);
  const int hw0 = blk * 8;
#pragma unroll
  for (int grp = 0; grp < 2; ++grp) {
    const int p0 = grp * 4;
    float4 xv[4];
#pragma unroll
    for (int q = 0; q < 4; ++q)
      xv[q] = *reinterpret_cast<const float4*>(
          x + (size_t)(hw0 + p0 + q + 128) * 1280 + c4);
#pragma unroll
    for (int q = 0; q < 4; ++q) {
      const int p = p0 + q;
      float4 a = make_float4(0.f, 0.f, 0.f, 0.f);
#pragma unroll
      for (int d = 0; d < 19; ++d) {
        const float f = cab[d * 16384 + hw0 + p];   // uniform -> s_load
        a.x = fmaf(mq[d].x, f, a.x);
        a.y = fmaf(mq[d].y, f, a.y);
        a.z = fmaf(mq[d].z, f, a.z);
        a.w = fmaf(mq[d].w, f, a.w);
      }
      float4 o4;
      o4.x = fmaxf(a.x, 0.f) + xv[q].x;
      o4.y = fmaxf(a.y, 0.f) + xv[q].y;
      o4.z = fmaxf(a.z, 0.f) + xv[q].z;
      o4.w = fmaxf(a.w, 0.f) + xv[q].w;
      const size_t addr = (size_t)(hw0 + p + 128) * 1280 + c4;
      *reinterpret_cast<float4*>(out + addr) = o4;
    }
  }
}

extern "C" void kernel_launch(void* const* d_in, const int* in_sizes, int n_in,
                              void* d_out, int out_size, void* d_ws, size_t ws_size,
                              hipStream_t stream)
{
  const float* x     = (const float*)d_in[0];
  const float* v1    = (const float*)d_in[1];
  const float* v2    = (const float*)d_in[2];
  const float* w1    = (const float*)d_in[3];
  const float* w2    = (const float*)d_in[4];
  const float* intra = (const float*)d_in[5];
  const float* inter = (const float*)d_in[6];
  const int*   ip    = (const int*)d_in[7];
  float* out = (float*)d_out;
  float* ws  = (float*)d_ws;

  prep_kernel<<<952, 256, 0, stream>>>(v1, v2, w1, w2, intra, inter, ip, x, out, ws);
  xm_kernel<<<256, 1024, 0, stream>>>(x, ws /*m1t*/, ws + OFF_XM);
  soft_kernel<<<256, 512, 0, stream>>>(ws + OFF_XM, ws + OFF_IMT, ws + OFF_IM2, ws + OFF_CAB);
  out_kernel<<<2048, 320, 0, stream>>>(x, ws + OFF_M2T, ws + OFF_CAB, out);
}

// Round 7
// 103.706 us; speedup vs baseline: 1.1635x; 1.1635x over previous
//
#include <hip/hip_runtime.h>

// B=1, H=W=128, C=1280; HW=16384 pixels, 19 relation channels, 1024 keys.
//
// Algebra: x_m = (v2@v1)·x   (M1: 19x1280, stored transposed m1t[c][o])
//          cab = softmax(x_m·imt^T)·im2, im2 = imt@inter  (1024x19)
//          out = relu((w2@w1)·cab) + x  (M2 stored transposed m2t[d][o])
//
// The chain is row-local (softmax is over keys, not pixels) -> fuse
// xm+soft+out into ONE kernel per 64-pixel block; xm/cab live in LDS.
//
// ws layout (floats):
//   m1t : [1280][20] (pad)       off 0       len 25600   (M1^T: m1t[c][o])
//   m2t : [19][1280]             off 25600   len 24320   (m2t[d][o])
//   imt : [1024][20] (pad)       off 49920   len 20480   (intra[i]^T)
//   im2 : [1024][20] (pad)       off 70400   len 20480   (imt @ inter[i])

#define OFF_M2T 25600
#define OFF_IMT 49920
#define OFF_IM2 70400

typedef float vf4 __attribute__((ext_vector_type(4)));

// prep: weight folds + transposes + cls-row copy (independent of everything else)
__global__ __launch_bounds__(256) void prep_kernel(
    const float* __restrict__ v1, const float* __restrict__ v2,
    const float* __restrict__ w1, const float* __restrict__ w2,
    const float* __restrict__ intra, const float* __restrict__ inter,
    const int* __restrict__ ip, const float* __restrict__ x,
    float* __restrict__ out, float* __restrict__ ws)
{
  float* m1t = ws;
  float* m2t = ws + OFF_M2T;
  float* imt = ws + OFF_IMT;
  float* im2 = ws + OFF_IM2;
  const int blk = blockIdx.x, tid = threadIdx.x;
  if (blk < 380) {
    // M1[o][j] = sum_c v2[o][c]*v1[c][j] -> stored m1t[j][o], 4-way c-split
    int g = blk * 256 + tid;
    int oidx = g >> 2, part = g & 3;
    int o = oidx / 1280, j = oidx - o * 1280;
    const float* v2r = v2 + o * 512 + part * 128;
    const float* v1c = v1 + part * 128 * 1280 + j;
    float acc = 0.f;
#pragma unroll 8
    for (int c = 0; c < 128; ++c) acc = fmaf(v2r[c], v1c[c * 1280], acc);
    acc += __shfl_xor(acc, 1);
    acc += __shfl_xor(acc, 2);
    if (part == 0) {
      m1t[j * 20 + o] = acc;
      if (o == 0) m1t[j * 20 + 19] = 0.f;
    }
  } else if (blk < 760) {
    // M2t[d][o] = sum_c w2[o][c]*w1[c][d]
    int g = (blk - 380) * 256 + tid;
    int oidx = g >> 2, part = g & 3;
    int o = oidx / 19, d = oidx - o * 19;
    const float* w2r = w2 + o * 512 + part * 128;
    const float* w1c = w1 + part * 128 * 19 + d;
    float acc = 0.f;
#pragma unroll 8
    for (int c = 0; c < 128; ++c) acc = fmaf(w2r[c], w1c[c * 19], acc);
    acc += __shfl_xor(acc, 1);
    acc += __shfl_xor(acc, 2);
    if (part == 0) m2t[d * 1280 + o] = acc;
  } else if (blk < 836) {
    // imt[k][c] = intra[i][c][k]
    int t = (blk - 760) * 256 + tid;
    int c = t >> 10, k = t & 1023;
    int iv = *ip;
    imt[k * 20 + c] = intra[(size_t)iv * 19456 + c * 1024 + k];
    if (c == 0) imt[k * 20 + 19] = 0.f;
  } else if (blk < 912) {
    // im2[k][d] = sum_c intra[i][c][k]*inter[i][c][d]
    int t = (blk - 836) * 256 + tid;
    int d = t >> 10, k = t & 1023;
    int iv = *ip;
    const float* ib = intra + (size_t)iv * 19456 + k;
    const float* ir = inter + (size_t)iv * 361 + d;
    float acc = 0.f;
#pragma unroll
    for (int c = 0; c < 19; ++c) acc = fmaf(ib[c * 1024], ir[c * 19], acc);
    im2[k * 20 + d] = acc;
    if (d == 0) im2[k * 20 + 19] = 0.f;
  } else {
    // cls row copy: out[0][w][c] = x[0][w][c], 40960 float4; 40 blocks x 4 each
    const float4* xf = reinterpret_cast<const float4*>(x);
    float4* of = reinterpret_cast<float4*>(out);
    const int base = (blk - 912) * 1024 + tid;
#pragma unroll
    for (int q = 0; q < 4; ++q) of[base + q * 256] = xf[base + q * 256];
  }
}

#define XM_FMA19(XC, W)                                                  \
  a00 = fmaf((XC), (W)[0],  a00); a01 = fmaf((XC), (W)[1],  a01);        \
  a02 = fmaf((XC), (W)[2],  a02); a03 = fmaf((XC), (W)[3],  a03);        \
  a04 = fmaf((XC), (W)[4],  a04); a05 = fmaf((XC), (W)[5],  a05);        \
  a06 = fmaf((XC), (W)[6],  a06); a07 = fmaf((XC), (W)[7],  a07);        \
  a08 = fmaf((XC), (W)[8],  a08); a09 = fmaf((XC), (W)[9],  a09);        \
  a10 = fmaf((XC), (W)[10], a10); a11 = fmaf((XC), (W)[11], a11);        \
  a12 = fmaf((XC), (W)[12], a12); a13 = fmaf((XC), (W)[13], a13);        \
  a14 = fmaf((XC), (W)[14], a14); a15 = fmaf((XC), (W)[15], a15);        \
  a16 = fmaf((XC), (W)[16], a16); a17 = fmaf((XC), (W)[17], a17);        \
  a18 = fmaf((XC), (W)[18], a18);

// Fused per-64-pixel-block kernel: 1024 threads, 1 block/CU (91.6 KB LDS).
// Phase 1: x (10 chunks of 128 c) -> LDS transpose -> xm[64][19] in LDS.
// Phase 2: 1024-key softmax (16 waves x 64 keys) -> cab[64][19] in LDS.
// Phase 3: out = relu(m2t.cab)+x, 960 thr = 3 px-groups x 320 c-quads,
//          coalesced x loads (L2/L3-hot) and nt float4 stores.
__global__ __launch_bounds__(1024) void fused_kernel(
    const float* __restrict__ x, const float* __restrict__ ws,
    float* __restrict__ out)
{
  const float* m1t = ws;
  const float* m2t = ws + OFF_M2T;
  const float* imt = ws + OFF_IMT;
  const float* im2 = ws + OFF_IM2;

  __shared__ float smem[20480];   // phase1: 2x8192 stage + 16x1216 reduce; phase2: red[16][64][20]
  __shared__ float xmr[1216];     // xm[px][19]
  __shared__ float cabs[1216];    // cab[px][19]

  const int blk = blockIdx.x, tid = threadIdx.x;
  const int p  = tid & 63;
  const int kp = tid >> 6;
  const int kpu = __builtin_amdgcn_readfirstlane(kp);
  const int n0 = blk * 64;
  const float* xg = x + (size_t)(n0 + 128) * 1280;

  // ---------------- Phase 1: xm = M1 . x ----------------
  {
    const int px0 = tid >> 5, g0 = tid & 31;
    const int px1 = px0 + 32;
    const size_t ga0 = (size_t)px0 * 1280 + g0 * 4;
    const size_t ga1 = (size_t)px1 * 1280 + g0 * 4;
    const int st0 = px0 * 128 + (((g0 + px0) & 31) << 2);
    const int st1 = px1 * 128 + (((g0 + px1) & 31) << 2);
    const int rd0 = p * 128 + ((((kpu * 2 + 0) + p) & 31) << 2);
    const int rd1 = p * 128 + ((((kpu * 2 + 1) + p) & 31) << 2);

    float a00 = 0.f, a01 = 0.f, a02 = 0.f, a03 = 0.f, a04 = 0.f;
    float a05 = 0.f, a06 = 0.f, a07 = 0.f, a08 = 0.f, a09 = 0.f;
    float a10 = 0.f, a11 = 0.f, a12 = 0.f, a13 = 0.f, a14 = 0.f;
    float a15 = 0.f, a16 = 0.f, a17 = 0.f, a18 = 0.f;

    {
      const float4 r0 = *reinterpret_cast<const float4*>(xg + ga0);
      const float4 r1 = *reinterpret_cast<const float4*>(xg + ga1);
      *reinterpret_cast<float4*>(smem + st0) = r0;
      *reinterpret_cast<float4*>(smem + st1) = r1;
    }
    __syncthreads();

    for (int cc = 0; cc < 10; ++cc) {
      float4 n0v, n1v;
      if (cc < 9) {                    // issue next-chunk loads early
        n0v = *reinterpret_cast<const float4*>(xg + ga0 + (cc + 1) * 128);
        n1v = *reinterpret_cast<const float4*>(xg + ga1 + (cc + 1) * 128);
      }
      const float* buf = smem + (cc & 1) * 8192;
      const float4 xv0 = *reinterpret_cast<const float4*>(buf + rd0);
      const float4 xv1 = *reinterpret_cast<const float4*>(buf + rd1);
      const float* wrow = m1t + (cc * 128 + kpu * 8) * 20;   // uniform -> s_load
      XM_FMA19(xv0.x, wrow);
      XM_FMA19(xv0.y, wrow + 20);
      XM_FMA19(xv0.z, wrow + 40);
      XM_FMA19(xv0.w, wrow + 60);
      XM_FMA19(xv1.x, wrow + 80);
      XM_FMA19(xv1.y, wrow + 100);
      XM_FMA19(xv1.z, wrow + 120);
      XM_FMA19(xv1.w, wrow + 140);
      if (cc < 9) {
        float* nbuf = smem + ((cc + 1) & 1) * 8192;
        *reinterpret_cast<float4*>(nbuf + st0) = n0v;
        *reinterpret_cast<float4*>(nbuf + st1) = n1v;
      }
      __syncthreads();
    }

    {
      float* rb = smem + kp * 1216 + p * 19;   // stride 19 coprime 32
      rb[0] = a00;  rb[1] = a01;  rb[2] = a02;  rb[3] = a03;  rb[4] = a04;
      rb[5] = a05;  rb[6] = a06;  rb[7] = a07;  rb[8] = a08;  rb[9] = a09;
      rb[10] = a10; rb[11] = a11; rb[12] = a12; rb[13] = a13; rb[14] = a14;
      rb[15] = a15; rb[16] = a16; rb[17] = a17; rb[18] = a18;
    }
    __syncthreads();
    for (int idx = tid; idx < 1216; idx += 1024) {
      const int o = idx >> 6, pp = idx & 63;
      float s = 0.f;
#pragma unroll
      for (int q = 0; q < 16; ++q) s += smem[q * 1216 + pp * 19 + o];
      xmr[pp * 19 + o] = s;
    }
    __syncthreads();
  }

  // ---------------- Phase 2: softmax over 1024 keys ----------------
  {
    const float* xr = xmr + p * 19;
    const float x00 = xr[0],  x01 = xr[1],  x02 = xr[2],  x03 = xr[3];
    const float x04 = xr[4],  x05 = xr[5],  x06 = xr[6],  x07 = xr[7];
    const float x08 = xr[8],  x09 = xr[9],  x10 = xr[10], x11 = xr[11];
    const float x12 = xr[12], x13 = xr[13], x14 = xr[14], x15 = xr[15];
    const float x16 = xr[16], x17 = xr[17], x18 = xr[18];

    float a00 = 0.f, a01 = 0.f, a02 = 0.f, a03 = 0.f, a04 = 0.f;
    float a05 = 0.f, a06 = 0.f, a07 = 0.f, a08 = 0.f, a09 = 0.f;
    float a10 = 0.f, a11 = 0.f, a12 = 0.f, a13 = 0.f, a14 = 0.f;
    float a15 = 0.f, a16 = 0.f, a17 = 0.f, a18 = 0.f;
    float Z = 0.f;
    const int kbase = kpu * 64;
    for (int k = kbase; k < kbase + 64; ++k) {
      const float* w = imt + k * 20;       // wave-uniform -> scalar loads
      const float* u = im2 + k * 20;
      float s0 = x00 * w[0];
      s0 = fmaf(x04, w[4],  s0); s0 = fmaf(x08, w[8],  s0);
      s0 = fmaf(x12, w[12], s0); s0 = fmaf(x16, w[16], s0);
      float s1 = x01 * w[1];
      s1 = fmaf(x05, w[5],  s1); s1 = fmaf(x09, w[9],  s1);
      s1 = fmaf(x13, w[13], s1); s1 = fmaf(x17, w[17], s1);
      float s2 = x02 * w[2];
      s2 = fmaf(x06, w[6],  s2); s2 = fmaf(x10, w[10], s2);
      s2 = fmaf(x14, w[14], s2); s2 = fmaf(x18, w[18], s2);
      float s3 = x03 * w[3];
      s3 = fmaf(x07, w[7],  s3); s3 = fmaf(x11, w[11], s3);
      s3 = fmaf(x15, w[15], s3);
      const float s = (s0 + s1) + (s2 + s3);
      const float pv = __expf(s);
      Z += pv;
      XM_FMA19(pv, u);
    }
    {
      float* rb = smem + kp * 1280 + p * 20;   // red[16][64][20]
      rb[0] = a00;  rb[1] = a01;  rb[2] = a02;  rb[3] = a03;  rb[4] = a04;
      rb[5] = a05;  rb[6] = a06;  rb[7] = a07;  rb[8] = a08;  rb[9] = a09;
      rb[10] = a10; rb[11] = a11; rb[12] = a12; rb[13] = a13; rb[14] = a14;
      rb[15] = a15; rb[16] = a16; rb[17] = a17; rb[18] = a18; rb[19] = Z;
    }
    __syncthreads();
    for (int idx = tid; idx < 1216; idx += 1024) {
      const int rr = idx / 19, d = idx - rr * 19;
      float s = 0.f, Zs = 0.f;
#pragma unroll
      for (int q = 0; q < 16; ++q) {
        s  += smem[q * 1280 + rr * 20 + d];
        Zs += smem[q * 1280 + rr * 20 + 19];
      }
      cabs[idx] = s / Zs;
    }
    __syncthreads();
  }

  // ---------------- Phase 3: out = relu(m2t . cab) + x ----------------
  if (tid < 960) {
    const int pg   = tid / 320;        // pixel group 0..2
    const int quad = tid - pg * 320;   // c-quad 0..319 (lane-consecutive)
    const int c4 = quad * 4;
    float4 mq[19];
#pragma unroll
    for (int d = 0; d < 19; ++d)
      mq[d] = *reinterpret_cast<const float4*>(m2t + d * 1280 + c4);
    for (int px = pg; px < 64; px += 3) {
      const float* cb = cabs + px * 19;          // wave-uniform -> broadcast
      const float4 xv = *reinterpret_cast<const float4*>(
          xg + (size_t)px * 1280 + c4);
      float4 a = make_float4(0.f, 0.f, 0.f, 0.f);
#pragma unroll
      for (int d = 0; d < 19; ++d) {
        const float f = cb[d];
        a.x = fmaf(mq[d].x, f, a.x);
        a.y = fmaf(mq[d].y, f, a.y);
        a.z = fmaf(mq[d].z, f, a.z);
        a.w = fmaf(mq[d].w, f, a.w);
      }
      vf4 o4;
      o4.x = fmaxf(a.x, 0.f) + xv.x;
      o4.y = fmaxf(a.y, 0.f) + xv.y;
      o4.z = fmaxf(a.z, 0.f) + xv.z;
      o4.w = fmaxf(a.w, 0.f) + xv.w;
      __builtin_nontemporal_store(
          o4, reinterpret_cast<vf4*>(out + (size_t)(n0 + px + 128) * 1280 + c4));
    }
  }
}

extern "C" void kernel_launch(void* const* d_in, const int* in_sizes, int n_in,
                              void* d_out, int out_size, void* d_ws, size_t ws_size,
                              hipStream_t stream)
{
  const float* x     = (const float*)d_in[0];
  const float* v1    = (const float*)d_in[1];
  const float* v2    = (const float*)d_in[2];
  const float* w1    = (const float*)d_in[3];
  const float* w2    = (const float*)d_in[4];
  const float* intra = (const float*)d_in[5];
  const float* inter = (const float*)d_in[6];
  const int*   ip    = (const int*)d_in[7];
  float* out = (float*)d_out;
  float* ws  = (float*)d_ws;

  prep_kernel<<<952, 256, 0, stream>>>(v1, v2, w1, w2, intra, inter, ip, x, out, ws);
  fused_kernel<<<256, 1024, 0, stream>>>(x, ws, out);
}